// Round 7
// baseline (198.379 us; speedup 1.0000x reference)
//
#include <hip/hip_runtime.h>
#include <stdint.h>

#define HIDDEN 1024
#define HEADS 16
#define HEAD_DIM 64
#define NBATCH 2
#define SEQ 2048

typedef short bh8 __attribute__((ext_vector_type(8)));    // 8 bf16 (MFMA x32 A/B frag)
typedef _Float16 hf4 __attribute__((ext_vector_type(4))); // 4 f16 (MFMA x16 A/B frag)
typedef _Float16 hf8 __attribute__((ext_vector_type(8))); // frag-pair (2x hf4)
typedef float fx4 __attribute__((ext_vector_type(4)));    // MFMA C/D frag

#define MFMA_BF16(a, b, c) __builtin_amdgcn_mfma_f32_16x16x32_bf16((a), (b), (c), 0, 0, 0)
#define MFMA_F16_16(a, b, c) __builtin_amdgcn_mfma_f32_16x16x16f16((a), (b), (c), 0, 0, 0)

__device__ __forceinline__ short f2bf(float f) {
  union { float f; uint32_t u; } v; v.f = f;
  uint32_t r = v.u + 0x7fffu + ((v.u >> 16) & 1u);
  return (short)(r >> 16);
}
__device__ __forceinline__ short f2h(float f) {
  union { _Float16 h; short s; } v; v.h = (_Float16)f;
  return v.s;
}

typedef __attribute__((address_space(1))) void GV;
typedef __attribute__((address_space(3))) void LV;
__device__ __forceinline__ void gl_lds16(const void* g, void* l) {
  __builtin_amdgcn_global_load_lds((GV*)g, (LV*)l, 16, 0, 0);
}

// Frag-ordered image offset (R4 notes): staging = contiguous 1KB chunks,
// LDS frag reads = base + g*1KB + lane*16B (conflict-free b128).
__device__ __forceinline__ size_t img_off(int row, int k) {
  int rt = row >> 7, kt = k >> 6;
  int g = (((row & 127) >> 4) << 1) + ((k & 63) >> 5);
  int l = (((k & 31) >> 3) << 4) + (row & 15);
  return ((size_t)((rt * 16 + kt) * 16 + g) << 9) + (l << 3) + (k & 7);
}

// ---------------------------------------------------------------------------
// Kernel 1: fp32 -> bf16 + frag-image scatter, 16B (full lane slot) stores.
// ---------------------------------------------------------------------------
__global__ void cvt_kernel(const float* __restrict__ x,
                           const float* __restrict__ wq, const float* __restrict__ wk,
                           const float* __restrict__ wv, const float* __restrict__ wo,
                           short* __restrict__ xb, short* __restrict__ wqb,
                           short* __restrict__ wkb, short* __restrict__ wvb,
                           short* __restrict__ wob) {
  long t = (long)blockIdx.x * blockDim.x + threadIdx.x;  // 0 .. 1M-1
  long i = t * 8;
  const float* s; short* d; long off;
  if (i < 4194304L) { s = x; d = xb; off = i; }
  else {
    long j = i - 4194304L;
    int w = (int)(j >> 20);
    off = j & 1048575L;
    s = (w == 0) ? wq : (w == 1) ? wk : (w == 2) ? wv : wo;
    d = (w == 0) ? wqb : (w == 1) ? wkb : (w == 2) ? wvb : wob;
  }
  float4 v0 = *(const float4*)(s + off);
  float4 v1 = *(const float4*)(s + off + 4);
  bh8 o;
  o[0] = f2bf(v0.x); o[1] = f2bf(v0.y); o[2] = f2bf(v0.z); o[3] = f2bf(v0.w);
  o[4] = f2bf(v1.x); o[5] = f2bf(v1.y); o[6] = f2bf(v1.z); o[7] = f2bf(v1.w);
  int row = (int)(off >> 10), k = (int)(off & 1023);  // k % 8 == 0
  *(bh8*)(d + img_off(row, k)) = o;
}

// ---------------------------------------------------------------------------
// Kernel 2: QKV projection. 128x128 tile, BK=64, frag-image inputs,
// XCD-swizzled 1D grid 768. EPILOGUE: C -> 32KB LDS image -> 8x16B coalesced
// global stores per thread (each block's output = 2 heads x 16KB contiguous).
// ---------------------------------------------------------------------------
__global__ __launch_bounds__(256)
void qkv_kernel(const short* __restrict__ xb,
                const short* __restrict__ wqb, const short* __restrict__ wkb,
                const short* __restrict__ wvb,
                const float* __restrict__ bq, const float* __restrict__ bk,
                const float* __restrict__ bv,
                short* __restrict__ Q, short* __restrict__ K, short* __restrict__ Vt) {
  __shared__ __align__(16) short smem[16384];  // A = [0,8192), B = [8192,16384)
  short* Alds = smem;
  short* Blds = smem + 8192;

  const int lin = blockIdx.x;
  const int xcd = lin & 7, idx = lin >> 3;
  const int mt = (xcd >> 1) * 8 + (idx & 7);        // 0..31 (128-row tiles)
  const int zo = (xcd & 1) * 12 + (idx >> 3);       // 0..23
  const int z = zo >> 3, ot = zo & 7;               // z matrix, 128-col tile

  const short* W = (z == 0) ? wqb : (z == 1) ? wkb : wvb;
  const float* bias = (z == 0) ? bq : (z == 1) ? bk : bv;
  const int tid = threadIdx.x;
  const int lane = tid & 63, w = tid >> 6;
  const int r = lane & 15, q = lane >> 4;
  const int wr = w >> 1, wc = w & 1;

  fx4 acc[4][4] = {};

  for (int kt = 0; kt < 16; ++kt) {
#pragma unroll
    for (int i = 0; i < 4; ++i) {
      int c = w * 4 + i;
      gl_lds16(xb + (((size_t)(mt * 16 + kt) * 16 + c) << 9) + lane * 8,
               (char*)Alds + c * 1024);
      gl_lds16(W + (((size_t)(ot * 16 + kt) * 16 + c) << 9) + lane * 8,
               (char*)Blds + c * 1024);
    }
    __syncthreads();
#pragma unroll
    for (int ks = 0; ks < 2; ++ks) {
      bh8 af[4], bf_[4];
#pragma unroll
      for (int ti = 0; ti < 4; ++ti)
        af[ti] = *(const bh8*)&Alds[(((wr * 4 + ti) * 2 + ks) << 9) + lane * 8];
#pragma unroll
      for (int tj = 0; tj < 4; ++tj)
        bf_[tj] = *(const bh8*)&Blds[(((wc * 4 + tj) * 2 + ks) << 9) + lane * 8];
#pragma unroll
      for (int ti = 0; ti < 4; ++ti)
#pragma unroll
        for (int tj = 0; tj < 4; ++tj)
          acc[ti][tj] = MFMA_BF16(af[ti], bf_[tj], acc[ti][tj]);
    }
    __syncthreads();
  }

  // ---- epilogue: C -> LDS (per-head image order) -> coalesced global ----
  const float QS = 0.18033688011112042f;  // 0.125 * log2(e)
#pragma unroll
  for (int ti = 0; ti < 4; ++ti)
#pragma unroll
    for (int tj = 0; tj < 4; ++tj)
#pragma unroll
      for (int i = 0; i < 4; ++i) {
        int nl = wr * 64 + ti * 16 + q * 4 + i;   // row-local 0..127
        int cl = wc * 64 + tj * 16 + r;           // col-local 0..127
        int hl = cl >> 6, d = cl & 63;
        float v = acc[ti][tj][i] + bias[ot * 128 + cl];
        short sv; int lo;
        if (z == 0) {
          sv = f2bf(v * QS);
          lo = hl * 8192 + nl * 64 + d;
        } else if (z == 1) {
          sv = f2bf(v);
          int g = ((nl >> 4) << 1) + (d >> 5);
          int lp = (((d & 31) >> 3) << 4) + (nl & 15);
          lo = hl * 8192 + g * 512 + lp * 8 + (d & 7);
        } else {
          sv = f2h(v);
          int dt = d >> 4, rp = d & 15;
          int ks2 = nl >> 4, pi = ks2 >> 1, hh = ks2 & 1;
          int qp = (nl & 15) >> 2, ii = nl & 3;
          lo = hl * 8192 + (dt * 4 + pi) * 512 + (qp * 16 + rp) * 8 + hh * 4 + ii;
        }
        smem[lo] = sv;
      }
  __syncthreads();
  {
    int b = mt >> 4;
    int n0 = (mt & 15) * 128;
    int jj = mt & 15;
    short* dst = (z == 0) ? Q : (z == 1) ? K : Vt;
#pragma unroll
    for (int kk = 0; kk < 8; ++kk) {
      int s = kk * 256 + tid;              // 16B slot, consecutive tid => coalesced
      int hl = s >> 10, inner = s & 1023;
      int bh = b * 16 + ot * 2 + hl;
      size_t go = (size_t)bh * 131072 +
                  (z == 0 ? (size_t)n0 * 64 : (size_t)jj * 8192) + (size_t)inner * 8;
      *(int4*)(dst + go) = *(const int4*)(smem + (size_t)s * 8);
    }
  }
}

// ---------------------------------------------------------------------------
// Kernel 3: transposed-flash attention (unchanged from R6): no-max softmax,
// double-buffered K/V frag-image staging, XCD-aware bh partitioning.
// ---------------------------------------------------------------------------
__global__ __launch_bounds__(512, 4)
void attn_kernel(const short* __restrict__ Q, const short* __restrict__ Kf,
                 const short* __restrict__ Vf, short* __restrict__ A) {
  __shared__ __align__(16) short Klds[2][8192];
  __shared__ __align__(16) short Vlds[2][8192];

  const int lin = blockIdx.x;
  const int xcd = lin & 7, idx = lin >> 3;   // idx: 0..63
  const int bh = xcd + 8 * (idx & 3);        // 4 bh per XCD
  const int n0 = (idx >> 2) * 128;

  const int tid = threadIdx.x;
  const int lane = tid & 63, w = tid >> 6;   // w: 0..7
  const int r = lane & 15, q = lane >> 4;

  const short* Qg = Q + (size_t)bh * 131072;
  const short* Kg = Kf + (size_t)bh * 131072;
  const short* Vg = Vf + (size_t)bh * 131072;

  bh8 qf[2];
#pragma unroll
  for (int ks = 0; ks < 2; ++ks)
    qf[ks] = *(const bh8*)(Qg + (size_t)(n0 + w * 16 + r) * 64 + ks * 32 + q * 8);

  fx4 o[4] = {};
  float l_run = 0.f;

#define ATTN_STAGE(j, b)                                                        \
  {                                                                             \
    const short* ktp = Kg + (j) * 8192;                                         \
    const short* vtp = Vg + (j) * 8192;                                         \
    _Pragma("unroll") for (int i = 0; i < 4; ++i) {                             \
      if (w < 4) {                                                              \
        int c = w * 4 + i;                                                      \
        gl_lds16(ktp + c * 512 + lane * 8, (char*)&Klds[b][0] + c * 1024);      \
      } else {                                                                  \
        int c = (w - 4) * 4 + i;                                                \
        gl_lds16(vtp + c * 512 + lane * 8, (char*)&Vlds[b][0] + c * 1024);      \
      }                                                                         \
    }                                                                           \
  }

  ATTN_STAGE(0, 0);
  __syncthreads();

  for (int j = 0; j < 16; ++j) {
    int cur = j & 1;
    if (j < 15) ATTN_STAGE(j + 1, cur ^ 1);

    fx4 s[8] = {};
#pragma unroll
    for (int ks = 0; ks < 2; ++ks)
#pragma unroll
      for (int tj = 0; tj < 8; ++tj) {
        bh8 kf = *(const bh8*)&Klds[cur][(tj * 2 + ks) * 512 + lane * 8];
        s[tj] = MFMA_BF16(kf, qf[ks], s[tj]);
      }

    hf4 p[8];
#pragma unroll
    for (int tj = 0; tj < 8; ++tj)
#pragma unroll
      for (int i = 0; i < 4; ++i) {
        float e = __builtin_amdgcn_exp2f(s[tj][i]);
        l_run += e;
        p[tj][i] = (_Float16)e;
      }

#pragma unroll
    for (int pi = 0; pi < 4; ++pi)
#pragma unroll
      for (int dt = 0; dt < 4; ++dt) {
        hf8 vv = *(const hf8*)&Vlds[cur][(dt * 4 + pi) * 512 + lane * 8];
        hf4 vlo = __builtin_shufflevector(vv, vv, 0, 1, 2, 3);
        hf4 vhi = __builtin_shufflevector(vv, vv, 4, 5, 6, 7);
        o[dt] = MFMA_F16_16(vlo, p[2 * pi], o[dt]);
        o[dt] = MFMA_F16_16(vhi, p[2 * pi + 1], o[dt]);
      }
    __syncthreads();
  }
#undef ATTN_STAGE

  float l = l_run;
  l += __shfl_xor(l, 16);
  l += __shfl_xor(l, 32);
  const float inv = 1.0f / l;

  const int h = bh & 15;
  const int mt = (bh >> 4) * 16 + (n0 >> 7);
#pragma unroll
  for (int dt = 0; dt < 4; ++dt) {
    short4 ov;
    ov.x = f2bf(o[dt][0] * inv);
    ov.y = f2bf(o[dt][1] * inv);
    ov.z = f2bf(o[dt][2] * inv);
    ov.w = f2bf(o[dt][3] * inv);
    int g = w * 2 + (dt >> 1);
    int lp = ((dt & 1) * 2 + (q >> 1)) * 16 + r;
    *(short4*)(A + (((size_t)(mt * 16 + h) * 16 + g) << 9) + lp * 8 + (q & 1) * 4) = ov;
  }
}

// ---------------------------------------------------------------------------
// Kernel 4: output projection. 64x64 tiles (grid 1024 = 4 blocks/CU,
// 4 waves/SIMD), frag-image inputs, XCD-swizzled, fp32 epilogue to d_out.
// ---------------------------------------------------------------------------
__global__ __launch_bounds__(256)
void proj_kernel(const short* __restrict__ ab, const short* __restrict__ wob,
                 const float* __restrict__ bo, float* __restrict__ out) {
  __shared__ __align__(16) short Alds[4096];  // 8 chunks x 1KB
  __shared__ __align__(16) short Blds[4096];

  const int lin = blockIdx.x;
  const int xcd = lin & 7, idx = lin >> 3;   // 0..127
  const int mt = xcd * 8 + (idx & 7);        // 0..63 (64-row tiles)
  const int ot = idx >> 3;                   // 0..15 (64-col tiles)

  const int tid = threadIdx.x;
  const int lane = tid & 63, w = tid >> 6;
  const int r = lane & 15, q = lane >> 4;
  const int wm = w & 1, wn = w >> 1;         // wave-tile 32x32
  const int rt = mt >> 1, rh = mt & 1;       // image 128-row tile + half
  const int st = ot >> 1, sh = ot & 1;

  fx4 acc[2][2] = {};

  for (int kt = 0; kt < 16; ++kt) {
#pragma unroll
    for (int i = 0; i < 2; ++i) {
      int c = w * 2 + i;  // 0..7
      gl_lds16(ab + (((size_t)(rt * 16 + kt) * 16 + rh * 8 + c) << 9) + lane * 8,
               (char*)Alds + c * 1024);
      gl_lds16(wob + (((size_t)(st * 16 + kt) * 16 + sh * 8 + c) << 9) + lane * 8,
               (char*)Blds + c * 1024);
    }
    __syncthreads();
#pragma unroll
    for (int ks = 0; ks < 2; ++ks) {
      bh8 af[2], bf_[2];
#pragma unroll
      for (int tm = 0; tm < 2; ++tm)
        af[tm] = *(const bh8*)&Alds[(((wm * 2 + tm) * 2 + ks) << 9) + lane * 8];
#pragma unroll
      for (int tn = 0; tn < 2; ++tn)
        bf_[tn] = *(const bh8*)&Blds[(((wn * 2 + tn) * 2 + ks) << 9) + lane * 8];
#pragma unroll
      for (int tm = 0; tm < 2; ++tm)
#pragma unroll
        for (int tn = 0; tn < 2; ++tn)
          acc[tm][tn] = MFMA_BF16(af[tm], bf_[tn], acc[tm][tn]);
    }
    __syncthreads();
  }

#pragma unroll
  for (int tm = 0; tm < 2; ++tm)
#pragma unroll
    for (int tn = 0; tn < 2; ++tn)
#pragma unroll
      for (int i = 0; i < 4; ++i) {
        int row = mt * 64 + wm * 32 + tm * 16 + q * 4 + i;
        int col = ot * 64 + wn * 32 + tn * 16 + r;
        out[(size_t)row * 1024 + col] = acc[tm][tn][i] + bo[col];
      }
}

// ---------------------------------------------------------------------------
extern "C" void kernel_launch(void* const* d_in, const int* in_sizes, int n_in,
                              void* d_out, int out_size, void* d_ws, size_t ws_size,
                              hipStream_t stream) {
  const float* x  = (const float*)d_in[0];
  const float* Wq = (const float*)d_in[1];
  const float* bq = (const float*)d_in[2];
  const float* Wk = (const float*)d_in[3];
  const float* bk = (const float*)d_in[4];
  const float* Wv = (const float*)d_in[5];
  const float* bv = (const float*)d_in[6];
  const float* Wo = (const float*)d_in[7];
  const float* bo = (const float*)d_in[8];
  float* out = (float*)d_out;
  char* ws = (char*)d_ws;

  short* xb  = (short*)(ws);
  short* wqb = (short*)(ws + 8388608);
  short* wkb = (short*)(ws + 8388608 + 2097152);
  short* wvb = (short*)(ws + 8388608 + 2 * 2097152);
  short* wob = (short*)(ws + 8388608 + 3 * 2097152);
  short* Qb  = (short*)(ws + 16777216);
  short* Kb  = (short*)(ws + 16777216 + 8388608);
  short* Vtb = (short*)(ws + 16777216 + 2 * 8388608);
  short* Ab  = (short*)(ws);  // alias xb (dead after qkv)

  cvt_kernel<<<4096, 256, 0, stream>>>(x, Wq, Wk, Wv, Wo, xb, wqb, wkb, wvb, wob);
  qkv_kernel<<<768, 256, 0, stream>>>(xb, wqb, wkb, wvb, bq, bk, bv, Qb, Kb, Vtb);
  attn_kernel<<<512, 512, 0, stream>>>(Qb, Kb, Vtb, Ab);
  proj_kernel<<<1024, 256, 0, stream>>>(Ab, wob, bo, out);
}

// Round 9
// 186.131 us; speedup vs baseline: 1.0658x; 1.0658x over previous
//
#include <hip/hip_runtime.h>
#include <stdint.h>

#define HIDDEN 1024
#define HEADS 16
#define HEAD_DIM 64
#define NBATCH 2
#define SEQ 2048

typedef short bh8 __attribute__((ext_vector_type(8)));    // 8 bf16 (MFMA x32 A/B frag)
typedef _Float16 hf4 __attribute__((ext_vector_type(4))); // 4 f16 (MFMA x16 A/B frag)
typedef _Float16 hf8 __attribute__((ext_vector_type(8))); // frag-pair (2x hf4)
typedef float fx4 __attribute__((ext_vector_type(4)));    // MFMA C/D frag

#define MFMA_BF16(a, b, c) __builtin_amdgcn_mfma_f32_16x16x32_bf16((a), (b), (c), 0, 0, 0)
#define MFMA_F16_16(a, b, c) __builtin_amdgcn_mfma_f32_16x16x16f16((a), (b), (c), 0, 0, 0)

__device__ __forceinline__ short f2bf(float f) {
  union { float f; uint32_t u; } v; v.f = f;
  uint32_t r = v.u + 0x7fffu + ((v.u >> 16) & 1u);
  return (short)(r >> 16);
}
__device__ __forceinline__ short f2h(float f) {
  union { _Float16 h; short s; } v; v.h = (_Float16)f;
  return v.s;
}

typedef __attribute__((address_space(1))) void GV;
typedef __attribute__((address_space(3))) void LV;
__device__ __forceinline__ void gl_lds16(const void* g, void* l) {
  __builtin_amdgcn_global_load_lds((GV*)g, (LV*)l, 16, 0, 0);
}

// Frag-ordered image offset (R4 notes): staging = contiguous 1KB chunks,
// LDS frag reads = base + g*1KB + lane*16B (conflict-free b128).
__device__ __forceinline__ size_t img_off(int row, int k) {
  int rt = row >> 7, kt = k >> 6;
  int g = (((row & 127) >> 4) << 1) + ((k & 63) >> 5);
  int l = (((k & 31) >> 3) << 4) + (row & 15);
  return ((size_t)((rt * 16 + kt) * 16 + g) << 9) + (l << 3) + (k & 7);
}

// ---------------------------------------------------------------------------
// Kernel 1: fp32 -> bf16 + frag-image scatter, 16B (full lane slot) stores.
// ---------------------------------------------------------------------------
__global__ void cvt_kernel(const float* __restrict__ x,
                           const float* __restrict__ wq, const float* __restrict__ wk,
                           const float* __restrict__ wv, const float* __restrict__ wo,
                           short* __restrict__ xb, short* __restrict__ wqb,
                           short* __restrict__ wkb, short* __restrict__ wvb,
                           short* __restrict__ wob) {
  long t = (long)blockIdx.x * blockDim.x + threadIdx.x;  // 0 .. 1M-1
  long i = t * 8;
  const float* s; short* d; long off;
  if (i < 4194304L) { s = x; d = xb; off = i; }
  else {
    long j = i - 4194304L;
    int w = (int)(j >> 20);
    off = j & 1048575L;
    s = (w == 0) ? wq : (w == 1) ? wk : (w == 2) ? wv : wo;
    d = (w == 0) ? wqb : (w == 1) ? wkb : (w == 2) ? wvb : wob;
  }
  float4 v0 = *(const float4*)(s + off);
  float4 v1 = *(const float4*)(s + off + 4);
  bh8 o;
  o[0] = f2bf(v0.x); o[1] = f2bf(v0.y); o[2] = f2bf(v0.z); o[3] = f2bf(v0.w);
  o[4] = f2bf(v1.x); o[5] = f2bf(v1.y); o[6] = f2bf(v1.z); o[7] = f2bf(v1.w);
  int row = (int)(off >> 10), k = (int)(off & 1023);  // k % 8 == 0
  *(bh8*)(d + img_off(row, k)) = o;
}

// ---------------------------------------------------------------------------
// Kernel 2: QKV projection, attn-shaped: 512 threads (8 waves, 4x2 wave grid),
// 128x128 tile, BK=64, DOUBLE-BUFFERED staging (64KB LDS, 2 blocks/CU),
// XCD-swizzled grid 768. Epilogue: C -> 32KB LDS image -> coalesced 16B stores.
// LDS layout: A0 @0, A1 @8192, B0 @16384, B1 @24576 (shorts).
// ---------------------------------------------------------------------------
__global__ __launch_bounds__(512)
void qkv_kernel(const short* __restrict__ xb,
                const short* __restrict__ wqb, const short* __restrict__ wkb,
                const short* __restrict__ wvb,
                const float* __restrict__ bq, const float* __restrict__ bk,
                const float* __restrict__ bv,
                short* __restrict__ Q, short* __restrict__ K, short* __restrict__ Vt) {
  __shared__ __align__(16) short smem[32768];

  const int lin = blockIdx.x;
  const int xcd = lin & 7, idx = lin >> 3;
  const int mt = (xcd >> 1) * 8 + (idx & 7);        // 0..31 (128-row tiles)
  const int zo = (xcd & 1) * 12 + (idx >> 3);       // 0..23
  const int z = zo >> 3, ot = zo & 7;               // matrix z, 128-col tile

  const short* W = (z == 0) ? wqb : (z == 1) ? wkb : wvb;
  const float* bias = (z == 0) ? bq : (z == 1) ? bk : bv;
  const int tid = threadIdx.x;
  const int lane = tid & 63, w = tid >> 6;          // w: 0..7
  const int r = lane & 15, q = lane >> 4;
  const int wr = w & 3, wc = w >> 2;                // 4 row-groups x 2 col-groups

  fx4 acc[2][4] = {};

#define QKV_STAGE(kt, b)                                                            \
  {                                                                                 \
    _Pragma("unroll") for (int i = 0; i < 4; ++i) {                                 \
      int c = w * 4 + i;                                                            \
      if (c < 16)                                                                   \
        gl_lds16(xb + (((size_t)(mt * 16 + (kt)) * 16 + c) << 9) + lane * 8,        \
                 (char*)smem + (size_t)(b) * 16384 + c * 1024);                     \
      else                                                                          \
        gl_lds16(W + (((size_t)(ot * 16 + (kt)) * 16 + (c - 16)) << 9) + lane * 8,  \
                 (char*)smem + 32768 + (size_t)(b) * 16384 + (c - 16) * 1024);      \
    }                                                                               \
  }

  QKV_STAGE(0, 0);
  __syncthreads();

  for (int kt = 0; kt < 16; ++kt) {
    int cur = kt & 1;
    if (kt < 15) QKV_STAGE(kt + 1, cur ^ 1);
    const short* Ab_ = smem + cur * 8192;
    const short* Bb_ = smem + 16384 + cur * 8192;
#pragma unroll
    for (int ks = 0; ks < 2; ++ks) {
      bh8 af[2], bf_[4];
#pragma unroll
      for (int tm = 0; tm < 2; ++tm)
        af[tm] = *(const bh8*)&Ab_[(((wr * 2 + tm) * 2 + ks) << 9) + lane * 8];
#pragma unroll
      for (int tn = 0; tn < 4; ++tn)
        bf_[tn] = *(const bh8*)&Bb_[(((wc * 4 + tn) * 2 + ks) << 9) + lane * 8];
#pragma unroll
      for (int tm = 0; tm < 2; ++tm)
#pragma unroll
        for (int tn = 0; tn < 4; ++tn)
          acc[tm][tn] = MFMA_BF16(af[tm], bf_[tn], acc[tm][tn]);
    }
    __syncthreads();
  }
#undef QKV_STAGE

  // ---- epilogue: C -> LDS (per-head image order) -> coalesced global ----
  const float QS = 0.18033688011112042f;  // 0.125 * log2(e)
#pragma unroll
  for (int tm = 0; tm < 2; ++tm)
#pragma unroll
    for (int tn = 0; tn < 4; ++tn)
#pragma unroll
      for (int i = 0; i < 4; ++i) {
        int nl = wr * 32 + tm * 16 + q * 4 + i;   // row-local 0..127
        int cl = wc * 64 + tn * 16 + r;           // col-local 0..127
        int hl = cl >> 6, d = cl & 63;
        float v = acc[tm][tn][i] + bias[ot * 128 + cl];
        short sv; int lo;
        if (z == 0) {
          sv = f2bf(v * QS);
          lo = hl * 8192 + nl * 64 + d;
        } else if (z == 1) {
          sv = f2bf(v);
          int g = ((nl >> 4) << 1) + (d >> 5);
          int lp = (((d & 31) >> 3) << 4) + (nl & 15);
          lo = hl * 8192 + g * 512 + lp * 8 + (d & 7);
        } else {
          sv = f2h(v);
          int dt = d >> 4, rp = d & 15;
          int ks2 = nl >> 4, pi = ks2 >> 1, hh = ks2 & 1;
          int qp = (nl & 15) >> 2, ii = nl & 3;
          lo = hl * 8192 + (dt * 4 + pi) * 512 + (qp * 16 + rp) * 8 + hh * 4 + ii;
        }
        smem[lo] = sv;  // safe: last compute barrier passed, all LDS reads done
      }
  __syncthreads();
  {
    int b = mt >> 4;
    int n0 = (mt & 15) * 128;
    int jj = mt & 15;
    short* dst = (z == 0) ? Q : (z == 1) ? K : Vt;
#pragma unroll
    for (int kk = 0; kk < 4; ++kk) {
      int s = kk * 512 + tid;              // 16B slot; consecutive tid => coalesced
      int hl = s >> 10, inner = s & 1023;
      int bh = b * 16 + ot * 2 + hl;
      size_t go = (size_t)bh * 131072 +
                  (z == 0 ? (size_t)n0 * 64 : (size_t)jj * 8192) + (size_t)inner * 8;
      *(int4*)(dst + go) = *(const int4*)(smem + (size_t)s * 8);
    }
  }
}

// ---------------------------------------------------------------------------
// Kernel 3: transposed-flash attention (unchanged from R6).
// ---------------------------------------------------------------------------
__global__ __launch_bounds__(512, 4)
void attn_kernel(const short* __restrict__ Q, const short* __restrict__ Kf,
                 const short* __restrict__ Vf, short* __restrict__ A) {
  __shared__ __align__(16) short Klds[2][8192];
  __shared__ __align__(16) short Vlds[2][8192];

  const int lin = blockIdx.x;
  const int xcd = lin & 7, idx = lin >> 3;   // idx: 0..63
  const int bh = xcd + 8 * (idx & 3);        // 4 bh per XCD
  const int n0 = (idx >> 2) * 128;

  const int tid = threadIdx.x;
  const int lane = tid & 63, w = tid >> 6;   // w: 0..7
  const int r = lane & 15, q = lane >> 4;

  const short* Qg = Q + (size_t)bh * 131072;
  const short* Kg = Kf + (size_t)bh * 131072;
  const short* Vg = Vf + (size_t)bh * 131072;

  bh8 qf[2];
#pragma unroll
  for (int ks = 0; ks < 2; ++ks)
    qf[ks] = *(const bh8*)(Qg + (size_t)(n0 + w * 16 + r) * 64 + ks * 32 + q * 8);

  fx4 o[4] = {};
  float l_run = 0.f;

#define ATTN_STAGE(j, b)                                                        \
  {                                                                             \
    const short* ktp = Kg + (j) * 8192;                                         \
    const short* vtp = Vg + (j) * 8192;                                         \
    _Pragma("unroll") for (int i = 0; i < 4; ++i) {                             \
      if (w < 4) {                                                              \
        int c = w * 4 + i;                                                      \
        gl_lds16(ktp + c * 512 + lane * 8, (char*)&Klds[b][0] + c * 1024);      \
      } else {                                                                  \
        int c = (w - 4) * 4 + i;                                                \
        gl_lds16(vtp + c * 512 + lane * 8, (char*)&Vlds[b][0] + c * 1024);      \
      }                                                                         \
    }                                                                           \
  }

  ATTN_STAGE(0, 0);
  __syncthreads();

  for (int j = 0; j < 16; ++j) {
    int cur = j & 1;
    if (j < 15) ATTN_STAGE(j + 1, cur ^ 1);

    fx4 s[8] = {};
#pragma unroll
    for (int ks = 0; ks < 2; ++ks)
#pragma unroll
      for (int tj = 0; tj < 8; ++tj) {
        bh8 kf = *(const bh8*)&Klds[cur][(tj * 2 + ks) * 512 + lane * 8];
        s[tj] = MFMA_BF16(kf, qf[ks], s[tj]);
      }

    hf4 p[8];
#pragma unroll
    for (int tj = 0; tj < 8; ++tj)
#pragma unroll
      for (int i = 0; i < 4; ++i) {
        float e = __builtin_amdgcn_exp2f(s[tj][i]);
        l_run += e;
        p[tj][i] = (_Float16)e;
      }

#pragma unroll
    for (int pi = 0; pi < 4; ++pi)
#pragma unroll
      for (int dt = 0; dt < 4; ++dt) {
        hf8 vv = *(const hf8*)&Vlds[cur][(dt * 4 + pi) * 512 + lane * 8];
        hf4 vlo = __builtin_shufflevector(vv, vv, 0, 1, 2, 3);
        hf4 vhi = __builtin_shufflevector(vv, vv, 4, 5, 6, 7);
        o[dt] = MFMA_F16_16(vlo, p[2 * pi], o[dt]);
        o[dt] = MFMA_F16_16(vhi, p[2 * pi + 1], o[dt]);
      }
    __syncthreads();
  }
#undef ATTN_STAGE

  float l = l_run;
  l += __shfl_xor(l, 16);
  l += __shfl_xor(l, 32);
  const float inv = 1.0f / l;

  const int h = bh & 15;
  const int mt = (bh >> 4) * 16 + (n0 >> 7);
#pragma unroll
  for (int dt = 0; dt < 4; ++dt) {
    short4 ov;
    ov.x = f2bf(o[dt][0] * inv);
    ov.y = f2bf(o[dt][1] * inv);
    ov.z = f2bf(o[dt][2] * inv);
    ov.w = f2bf(o[dt][3] * inv);
    int g = w * 2 + (dt >> 1);
    int lp = ((dt & 1) * 2 + (q >> 1)) * 16 + r;
    *(short4*)(A + (((size_t)(mt * 16 + h) * 16 + g) << 9) + lp * 8 + (q & 1) * 4) = ov;
  }
}

// ---------------------------------------------------------------------------
// Kernel 4: output projection. 64x64 tiles, grid 1024 (4 blocks/CU),
// DOUBLE-BUFFERED (32KB LDS), frag-image inputs, XCD-swizzled, fp32 out.
// ---------------------------------------------------------------------------
__global__ __launch_bounds__(256)
void proj_kernel(const short* __restrict__ ab, const short* __restrict__ wob,
                 const float* __restrict__ bo, float* __restrict__ out) {
  __shared__ __align__(16) short Alds[2][4096];
  __shared__ __align__(16) short Blds[2][4096];

  const int lin = blockIdx.x;
  const int xcd = lin & 7, idx = lin >> 3;   // 0..127
  const int mt = xcd * 8 + (idx & 7);        // 0..63 (64-row tiles)
  const int ot = idx >> 3;                   // 0..15 (64-col tiles)

  const int tid = threadIdx.x;
  const int lane = tid & 63, w = tid >> 6;
  const int r = lane & 15, q = lane >> 4;
  const int wm = w & 1, wn = w >> 1;         // wave-tile 32x32
  const int rt = mt >> 1, rh = mt & 1;       // image 128-row tile + half
  const int st = ot >> 1, sh = ot & 1;

  fx4 acc[2][2] = {};

#define PROJ_STAGE(kt, b)                                                            \
  {                                                                                  \
    _Pragma("unroll") for (int i = 0; i < 4; ++i) {                                  \
      int c = w * 4 + i;                                                             \
      if (c < 8)                                                                     \
        gl_lds16(ab + (((size_t)(rt * 16 + (kt)) * 16 + rh * 8 + c) << 9) + lane * 8,\
                 (char*)&Alds[b][0] + c * 1024);                                     \
      else                                                                           \
        gl_lds16(wob + (((size_t)(st * 16 + (kt)) * 16 + sh * 8 + (c - 8)) << 9) + lane * 8, \
                 (char*)&Blds[b][0] + (c - 8) * 1024);                               \
    }                                                                                \
  }

  PROJ_STAGE(0, 0);
  __syncthreads();

  for (int kt = 0; kt < 16; ++kt) {
    int cur = kt & 1;
    if (kt < 15) PROJ_STAGE(kt + 1, cur ^ 1);
#pragma unroll
    for (int ks = 0; ks < 2; ++ks) {
      bh8 af[2], bf_[2];
#pragma unroll
      for (int tm = 0; tm < 2; ++tm)
        af[tm] = *(const bh8*)&Alds[cur][(((wm * 2 + tm) * 2 + ks) << 9) + lane * 8];
#pragma unroll
      for (int tn = 0; tn < 2; ++tn)
        bf_[tn] = *(const bh8*)&Blds[cur][(((wn * 2 + tn) * 2 + ks) << 9) + lane * 8];
#pragma unroll
      for (int tm = 0; tm < 2; ++tm)
#pragma unroll
        for (int tn = 0; tn < 2; ++tn)
          acc[tm][tn] = MFMA_BF16(af[tm], bf_[tn], acc[tm][tn]);
    }
    __syncthreads();
  }
#undef PROJ_STAGE

#pragma unroll
  for (int tm = 0; tm < 2; ++tm)
#pragma unroll
    for (int tn = 0; tn < 2; ++tn)
#pragma unroll
      for (int i = 0; i < 4; ++i) {
        int row = mt * 64 + wm * 32 + tm * 16 + q * 4 + i;
        int col = ot * 64 + wn * 32 + tn * 16 + r;
        out[(size_t)row * 1024 + col] = acc[tm][tn][i] + bo[col];
      }
}

// ---------------------------------------------------------------------------
extern "C" void kernel_launch(void* const* d_in, const int* in_sizes, int n_in,
                              void* d_out, int out_size, void* d_ws, size_t ws_size,
                              hipStream_t stream) {
  const float* x  = (const float*)d_in[0];
  const float* Wq = (const float*)d_in[1];
  const float* bq = (const float*)d_in[2];
  const float* Wk = (const float*)d_in[3];
  const float* bk = (const float*)d_in[4];
  const float* Wv = (const float*)d_in[5];
  const float* bv = (const float*)d_in[6];
  const float* Wo = (const float*)d_in[7];
  const float* bo = (const float*)d_in[8];
  float* out = (float*)d_out;
  char* ws = (char*)d_ws;

  short* xb  = (short*)(ws);
  short* wqb = (short*)(ws + 8388608);
  short* wkb = (short*)(ws + 8388608 + 2097152);
  short* wvb = (short*)(ws + 8388608 + 2 * 2097152);
  short* wob = (short*)(ws + 8388608 + 3 * 2097152);
  short* Qb  = (short*)(ws + 16777216);
  short* Kb  = (short*)(ws + 16777216 + 8388608);
  short* Vtb = (short*)(ws + 16777216 + 2 * 8388608);
  short* Ab  = (short*)(ws);  // alias xb (dead after qkv)

  cvt_kernel<<<4096, 256, 0, stream>>>(x, Wq, Wk, Wv, Wo, xb, wqb, wkb, wvb, wob);
  qkv_kernel<<<768, 512, 0, stream>>>(xb, wqb, wkb, wvb, bq, bk, bv, Qb, Kb, Vtb);
  attn_kernel<<<512, 512, 0, stream>>>(Qb, Kb, Vtb, Ab);
  proj_kernel<<<1024, 256, 0, stream>>>(Ab, wob, bo, out);
}